// Round 1
// baseline (1429.655 us; speedup 1.0000x reference)
//
#include <hip/hip_runtime.h>

#define NEG 0.2f

// wke[h*64+k] = sum_c W_edge[k][h*32+c] * att_edge[h][c]
__global__ void k_wke(const float* __restrict__ W_edge, const float* __restrict__ att_edge,
                      float* __restrict__ wke) {
    int t = threadIdx.x;          // 0..127
    int hh = t >> 6;              // head
    int k  = t & 63;              // edge-dim index
    float s = 0.f;
#pragma unroll
    for (int c = 0; c < 32; ++c)
        s += W_edge[k * 64 + hh * 32 + c] * att_edge[hh * 32 + c];
    wke[hh * 64 + k] = s;
}

// h = relu(x) @ W ; a_src/a_dst via shuffle reduce. 64 nodes per 256-thread block.
__global__ __launch_bounds__(256) void k_node(
    const float* __restrict__ x, const float* __restrict__ W,
    const float* __restrict__ att_src, const float* __restrict__ att_dst,
    float* __restrict__ hbuf, float* __restrict__ a_src, float* __restrict__ a_dst, int N) {
    __shared__ float Wl[128 * 64];
    __shared__ float xs[4 * 128];
    int t = threadIdx.x;
    for (int i = t; i < 128 * 64; i += 256) Wl[i] = W[i];
    int col = t & 63;
    int nl  = t >> 6;             // 0..3 node-within-quad
    float asw = att_src[col];
    float adw = att_dst[col];
    int node0 = blockIdx.x * 64;
    __syncthreads();
    for (int it = 0; it < 16; ++it) {
        int nb = node0 + it * 4;
        __syncthreads();
        for (int j = t; j < 512; j += 256) {
            int nn = nb + (j >> 7);
            int k  = j & 127;
            xs[j] = (nn < N) ? fmaxf(x[(size_t)nn * 128 + k], 0.f) : 0.f;
        }
        __syncthreads();
        int n = nb + nl;
        float acc = 0.f;
#pragma unroll 8
        for (int k = 0; k < 128; ++k)
            acc = fmaf(xs[nl * 128 + k], Wl[k * 64 + col], acc);
        float vs = acc * asw, vd = acc * adw;
#pragma unroll
        for (int m = 1; m <= 16; m <<= 1) {
            vs += __shfl_xor(vs, m, 64);
            vd += __shfl_xor(vd, m, 64);
        }
        if (n < N) {
            hbuf[(size_t)n * 64 + col] = acc;
            if ((col & 31) == 0) {
                int hh = col >> 5;
                a_src[n * 2 + hh] = vs;
                a_dst[n * 2 + hh] = vd;
            }
        }
    }
}

// One sweep over edges: a_edge dot, logits, exp, atomic aggregation.
// 16 lanes per edge, 4 edges per wave-iteration, grid-stride.
__global__ __launch_bounds__(256) void k_edge(
    const float* __restrict__ edge_attr, const int* __restrict__ srcI,
    const int* __restrict__ dstI, const float* __restrict__ wke,
    const float* __restrict__ a_src, const float* __restrict__ a_dst,
    const float* __restrict__ hbuf,
    float* __restrict__ deg, float* __restrict__ sum_ae,
    float* __restrict__ denom, float* __restrict__ accb,
    long long E, int nwaves_total) {
    int lane = threadIdx.x & 63;
    int sub  = lane & 15;
    int grp  = lane >> 4;
    long long wave = (long long)blockIdx.x * 4 + (threadIdx.x >> 6);
    float w0[4], w1[4];
#pragma unroll
    for (int j = 0; j < 4; ++j) {
        w0[j] = wke[sub * 4 + j];
        w1[j] = wke[64 + sub * 4 + j];
    }
    for (long long base = wave * 4; base < E; base += (long long)nwaves_total * 4) {
        long long e = base + grp;
        bool valid = e < E;
        float pa0 = 0.f, pa1 = 0.f;
        if (valid) {
            const float4 ea = *(const float4*)(edge_attr + e * 64 + sub * 4);
            pa0 = ea.x * w0[0] + ea.y * w0[1] + ea.z * w0[2] + ea.w * w0[3];
            pa1 = ea.x * w1[0] + ea.y * w1[1] + ea.z * w1[2] + ea.w * w1[3];
        }
#pragma unroll
        for (int m = 1; m <= 8; m <<= 1) {
            pa0 += __shfl_xor(pa0, m, 64);
            pa1 += __shfl_xor(pa1, m, 64);
        }
        if (valid) {
            int s = srcI[e], d = dstI[e];
            float l0 = a_src[s * 2 + 0] + a_dst[d * 2 + 0] + pa0;
            float l1 = a_src[s * 2 + 1] + a_dst[d * 2 + 1] + pa1;
            l0 = l0 > 0.f ? l0 : NEG * l0;
            l1 = l1 > 0.f ? l1 : NEG * l1;
            float q0 = __expf(l0), q1 = __expf(l1);
            const float4 hv = *(const float4*)(hbuf + (size_t)s * 64 + sub * 4);
            float q = (sub < 8) ? q0 : q1;   // head = (sub*4)/32
            float* ap = accb + (size_t)d * 64 + sub * 4;
            atomicAdd(ap + 0, q * hv.x);
            atomicAdd(ap + 1, q * hv.y);
            atomicAdd(ap + 2, q * hv.z);
            atomicAdd(ap + 3, q * hv.w);
            if (sub == 0) {
                atomicAdd(&denom[d * 2 + 0], q0);
                atomicAdd(&denom[d * 2 + 1], q1);
                atomicAdd(&sum_ae[d * 2 + 0], pa0);
                atomicAdd(&sum_ae[d * 2 + 1], pa1);
                atomicAdd(&deg[d], 1.0f);
            }
        }
    }
}

// Self-loop contribution + normalize + bias.
__global__ void k_final(const float* __restrict__ hbuf, const float* __restrict__ a_src,
                        const float* __restrict__ a_dst, const float* __restrict__ deg,
                        const float* __restrict__ sum_ae, const float* __restrict__ denom,
                        const float* __restrict__ accb, const float* __restrict__ bias,
                        float* __restrict__ out, int N) {
    int t = blockIdx.x * 256 + threadIdx.x;
    if (t >= N * 64) return;
    int n = t >> 6, col = t & 63, hh = col >> 5;
    float dg  = fmaxf(deg[n], 1.0f);
    float ael = sum_ae[n * 2 + hh] / dg;
    float lg  = a_src[n * 2 + hh] + a_dst[n * 2 + hh] + ael;
    lg = lg > 0.f ? lg : NEG * lg;
    float pl = __expf(lg);
    out[t] = (accb[t] + pl * hbuf[t]) / (denom[n * 2 + hh] + pl + 1e-16f) + bias[col];
}

extern "C" void kernel_launch(void* const* d_in, const int* in_sizes, int n_in,
                              void* d_out, int out_size, void* d_ws, size_t ws_size,
                              hipStream_t stream) {
    const float* x         = (const float*)d_in[0];
    const int*   ei        = (const int*)d_in[1];
    const float* edge_attr = (const float*)d_in[2];
    const float* W         = (const float*)d_in[3];
    const float* W_edge    = (const float*)d_in[4];
    const float* att_src   = (const float*)d_in[5];
    const float* att_dst   = (const float*)d_in[6];
    const float* att_edge  = (const float*)d_in[7];
    const float* bias      = (const float*)d_in[8];

    int N = in_sizes[0] / 128;
    long long E = in_sizes[1] / 2;
    const int* srcI = ei;
    const int* dstI = ei + E;

    float* ws    = (float*)d_ws;
    float* wke   = ws;                          // 128
    float* hbuf  = ws + 128;                    // N*64
    float* a_src = hbuf + (size_t)N * 64;       // N*2
    float* a_dst = a_src + (size_t)N * 2;       // N*2
    float* zero0 = a_dst + (size_t)N * 2;
    float* deg   = zero0;                       // N
    float* sum_ae = deg + N;                    // N*2
    float* denom  = sum_ae + (size_t)N * 2;     // N*2
    float* accb   = denom + (size_t)N * 2;      // N*64

    size_t zbytes = (size_t)N * (1 + 2 + 2 + 64) * sizeof(float);
    hipMemsetAsync(zero0, 0, zbytes, stream);

    k_wke<<<1, 128, 0, stream>>>(W_edge, att_edge, wke);
    k_node<<<(N + 63) / 64, 256, 0, stream>>>(x, W, att_src, att_dst, hbuf, a_src, a_dst, N);

    int nblocks = 2048;
    k_edge<<<nblocks, 256, 0, stream>>>(edge_attr, srcI, dstI, wke, a_src, a_dst, hbuf,
                                        deg, sum_ae, denom, accb, E, nblocks * 4);

    k_final<<<((N * 64) + 255) / 256, 256, 0, stream>>>(hbuf, a_src, a_dst, deg, sum_ae,
                                                        denom, accb, bias, (float*)d_out, N);
}

// Round 2
// 310.169 us; speedup vs baseline: 4.6093x; 4.6093x over previous
//
#include <hip/hip_runtime.h>

#define NEG 0.2f

// wke[h*64+k] = sum_c W_edge[k][h*32+c] * att_edge[h][c]
__global__ void k_wke(const float* __restrict__ W_edge, const float* __restrict__ att_edge,
                      float* __restrict__ wke) {
    int t = threadIdx.x;          // 0..127
    int hh = t >> 6;              // head
    int k  = t & 63;              // edge-dim index
    float s = 0.f;
#pragma unroll
    for (int c = 0; c < 32; ++c)
        s += W_edge[k * 64 + hh * 32 + c] * att_edge[hh * 32 + c];
    wke[hh * 64 + k] = s;
}

// h = relu(x) @ W ; a_src/a_dst via shuffle reduce. 64 nodes per 256-thread block.
__global__ __launch_bounds__(256) void k_node(
    const float* __restrict__ x, const float* __restrict__ W,
    const float* __restrict__ att_src, const float* __restrict__ att_dst,
    float* __restrict__ hbuf, float* __restrict__ a_src, float* __restrict__ a_dst, int N) {
    __shared__ float Wl[128 * 64];
    __shared__ float xs[4 * 128];
    int t = threadIdx.x;
    for (int i = t; i < 128 * 64; i += 256) Wl[i] = W[i];
    int col = t & 63;
    int nl  = t >> 6;             // 0..3 node-within-quad
    float asw = att_src[col];
    float adw = att_dst[col];
    int node0 = blockIdx.x * 64;
    __syncthreads();
    for (int it = 0; it < 16; ++it) {
        int nb = node0 + it * 4;
        __syncthreads();
        for (int j = t; j < 512; j += 256) {
            int nn = nb + (j >> 7);
            int k  = j & 127;
            xs[j] = (nn < N) ? fmaxf(x[(size_t)nn * 128 + k], 0.f) : 0.f;
        }
        __syncthreads();
        int n = nb + nl;
        float acc = 0.f;
#pragma unroll 8
        for (int k = 0; k < 128; ++k)
            acc = fmaf(xs[nl * 128 + k], Wl[k * 64 + col], acc);
        float vs = acc * asw, vd = acc * adw;
#pragma unroll
        for (int m = 1; m <= 16; m <<= 1) {
            vs += __shfl_xor(vs, m, 64);
            vd += __shfl_xor(vd, m, 64);
        }
        if (n < N) {
            hbuf[(size_t)n * 64 + col] = acc;
            if ((col & 31) == 0) {
                int hh = col >> 5;
                a_src[n * 2 + hh] = vs;
                a_dst[n * 2 + hh] = vd;
            }
        }
    }
}

// In-degree histogram: 1 int atomic per edge.
__global__ __launch_bounds__(256) void k_hist(const int* __restrict__ dstI, int* __restrict__ count,
                                              long long E) {
    long long i0 = (long long)blockIdx.x * 256 + threadIdx.x;
    long long stride = (long long)gridDim.x * 256;
    for (long long i = i0; i < E; i += stride)
        atomicAdd(&count[dstI[i]], 1);
}

// Exclusive scan, 1024 elements per block (256 thr x 4).
__global__ __launch_bounds__(256) void k_scan1(const int* __restrict__ cnt, int* __restrict__ offs,
                                               int* __restrict__ bsum, int N) {
    __shared__ int ts[256];
    int t = threadIdx.x, blk = blockIdx.x;
    int base = blk * 1024 + t * 4;
    int v[4], s = 0;
#pragma unroll
    for (int i = 0; i < 4; ++i) {
        int idx = base + i;
        v[i] = (idx < N) ? cnt[idx] : 0;
        s += v[i];
    }
    ts[t] = s;
    __syncthreads();
    for (int off = 1; off < 256; off <<= 1) {
        int y = (t >= off) ? ts[t - off] : 0;
        __syncthreads();
        ts[t] += y;
        __syncthreads();
    }
    int run = ts[t] - s;   // exclusive prefix of this thread's chunk
#pragma unroll
    for (int i = 0; i < 4; ++i) {
        int idx = base + i;
        if (idx < N) offs[idx] = run;
        run += v[i];
    }
    if (t == 255) bsum[blk] = ts[255];
}

__global__ void k_scan2(int* __restrict__ bsum, int nb) {
    if (threadIdx.x == 0) {
        int run = 0;
        for (int i = 0; i < nb; ++i) { int v = bsum[i]; bsum[i] = run; run += v; }
    }
}

__global__ void k_scan3(int* __restrict__ offs, const int* __restrict__ bsum,
                        int* __restrict__ cursor, int N) {
    int idx = blockIdx.x * 256 + threadIdx.x;
    if (idx < N) {
        int o = offs[idx] + bsum[idx >> 10];
        offs[idx] = o;
        cursor[idx] = o;
    }
}

// Edge sweep: a_edge dot (16-lane reduce over edge_attr row) + CSR scatter.
__global__ __launch_bounds__(256) void k_pa(
    const float* __restrict__ edge_attr, const int* __restrict__ srcI,
    const int* __restrict__ dstI, const float* __restrict__ wke,
    int* __restrict__ cursor, int* __restrict__ srcperm, float2* __restrict__ paperm,
    long long E, int nwaves_total) {
    int lane = threadIdx.x & 63;
    int sub  = lane & 15;
    int grp  = lane >> 4;
    long long wave = (long long)blockIdx.x * 4 + (threadIdx.x >> 6);
    float w0[4], w1[4];
#pragma unroll
    for (int j = 0; j < 4; ++j) {
        w0[j] = wke[sub * 4 + j];
        w1[j] = wke[64 + sub * 4 + j];
    }
    for (long long base = wave * 4; base < E; base += (long long)nwaves_total * 4) {
        long long e = base + grp;
        bool valid = e < E;
        float pa0 = 0.f, pa1 = 0.f;
        if (valid) {
            const float4 ea = *(const float4*)(edge_attr + e * 64 + sub * 4);
            pa0 = ea.x * w0[0] + ea.y * w0[1] + ea.z * w0[2] + ea.w * w0[3];
            pa1 = ea.x * w1[0] + ea.y * w1[1] + ea.z * w1[2] + ea.w * w1[3];
        }
#pragma unroll
        for (int m = 1; m <= 8; m <<= 1) {
            pa0 += __shfl_xor(pa0, m, 64);
            pa1 += __shfl_xor(pa1, m, 64);
        }
        if (valid && sub == 0) {
            int s = srcI[e], d = dstI[e];
            int pos = atomicAdd(&cursor[d], 1);
            srcperm[pos] = s;
            paperm[pos] = make_float2(pa0, pa1);
        }
    }
}

// Per-node aggregation over its CSR list: zero atomics, registers only.
// 16 lanes per node, 16 nodes per 256-thread block.
__global__ __launch_bounds__(256) void k_agg(
    const int* __restrict__ srcperm, const float2* __restrict__ paperm,
    const int* __restrict__ offs, const int* __restrict__ count,
    const float* __restrict__ a_src, const float* __restrict__ a_dst,
    const float* __restrict__ hbuf, const float* __restrict__ bias,
    float* __restrict__ out, int N) {
    int t = threadIdx.x;
    int sub = t & 15;
    int n = blockIdx.x * 16 + (t >> 4);
    if (n >= N) return;
    int cnt  = count[n];
    int base = offs[n];
    float ad0 = a_dst[n * 2 + 0], ad1 = a_dst[n * 2 + 1];
    float accx = 0.f, accy = 0.f, accz = 0.f, accw = 0.f;
    float den0 = 0.f, den1 = 0.f, sae0 = 0.f, sae1 = 0.f;

    int   sj  = (cnt > 0) ? srcperm[base] : 0;
    float2 paj = (cnt > 0) ? paperm[base] : make_float2(0.f, 0.f);
    for (int j = 0; j < cnt; ++j) {
        int   snext  = (j + 1 < cnt) ? srcperm[base + j + 1] : 0;
        float2 panext = (j + 1 < cnt) ? paperm[base + j + 1] : make_float2(0.f, 0.f);
        float as0 = a_src[sj * 2 + 0], as1 = a_src[sj * 2 + 1];
        float l0 = as0 + ad0 + paj.x; l0 = l0 > 0.f ? l0 : NEG * l0;
        float l1 = as1 + ad1 + paj.y; l1 = l1 > 0.f ? l1 : NEG * l1;
        float q0 = __expf(l0), q1 = __expf(l1);
        const float4 hv = *(const float4*)(hbuf + (size_t)sj * 64 + sub * 4);
        float q = (sub < 8) ? q0 : q1;
        accx = fmaf(q, hv.x, accx);
        accy = fmaf(q, hv.y, accy);
        accz = fmaf(q, hv.z, accz);
        accw = fmaf(q, hv.w, accw);
        den0 += q0; den1 += q1;
        sae0 += paj.x; sae1 += paj.y;
        sj = snext; paj = panext;
    }
    float dg = (cnt > 0) ? (float)cnt : 1.f;
    float l0 = a_src[n * 2 + 0] + ad0 + sae0 / dg; l0 = l0 > 0.f ? l0 : NEG * l0;
    float l1 = a_src[n * 2 + 1] + ad1 + sae1 / dg; l1 = l1 > 0.f ? l1 : NEG * l1;
    float pl0 = __expf(l0), pl1 = __expf(l1);
    const float4 hn = *(const float4*)(hbuf + (size_t)n * 64 + sub * 4);
    float pl  = (sub < 8) ? pl0 : pl1;
    float den = ((sub < 8) ? den0 + pl0 : den1 + pl1) + 1e-16f;
    const float4 bv = *(const float4*)(bias + sub * 4);
    float4 o;
    o.x = (accx + pl * hn.x) / den + bv.x;
    o.y = (accy + pl * hn.y) / den + bv.y;
    o.z = (accz + pl * hn.z) / den + bv.z;
    o.w = (accw + pl * hn.w) / den + bv.w;
    *(float4*)(out + (size_t)n * 64 + sub * 4) = o;
}

extern "C" void kernel_launch(void* const* d_in, const int* in_sizes, int n_in,
                              void* d_out, int out_size, void* d_ws, size_t ws_size,
                              hipStream_t stream) {
    const float* x         = (const float*)d_in[0];
    const int*   ei        = (const int*)d_in[1];
    const float* edge_attr = (const float*)d_in[2];
    const float* W         = (const float*)d_in[3];
    const float* W_edge    = (const float*)d_in[4];
    const float* att_src   = (const float*)d_in[5];
    const float* att_dst   = (const float*)d_in[6];
    const float* att_edge  = (const float*)d_in[7];
    const float* bias      = (const float*)d_in[8];

    int N = in_sizes[0] / 128;
    long long E = in_sizes[1] / 2;
    const int* srcI = ei;
    const int* dstI = ei + E;

    // Workspace layout (floats/ints, 4B each)
    char* ws = (char*)d_ws;
    float* wke     = (float*)ws;                      ws += 128 * 4;
    float* hbuf    = (float*)ws;                      ws += (size_t)N * 64 * 4;
    float* a_src   = (float*)ws;                      ws += (size_t)N * 2 * 4;
    float* a_dst   = (float*)ws;                      ws += (size_t)N * 2 * 4;
    float2* paperm = (float2*)ws;                     ws += (size_t)E * 2 * 4;
    int*   srcperm = (int*)ws;                        ws += (size_t)E * 4;
    int*   count   = (int*)ws;                        ws += (size_t)N * 4;
    int*   offs    = (int*)ws;                        ws += (size_t)N * 4;
    int*   cursor  = (int*)ws;                        ws += (size_t)N * 4;
    int*   bsum    = (int*)ws;                        ws += 64 * 4;

    hipMemsetAsync(count, 0, (size_t)N * sizeof(int), stream);

    k_wke<<<1, 128, 0, stream>>>(W_edge, att_edge, wke);
    k_node<<<(N + 63) / 64, 256, 0, stream>>>(x, W, att_src, att_dst, hbuf, a_src, a_dst, N);
    k_hist<<<2048, 256, 0, stream>>>(dstI, count, E);

    int nb = (N + 1023) / 1024;
    k_scan1<<<nb, 256, 0, stream>>>(count, offs, bsum, N);
    k_scan2<<<1, 64, 0, stream>>>(bsum, nb);
    k_scan3<<<(N + 255) / 256, 256, 0, stream>>>(offs, bsum, cursor, N);

    int nblocks = 2048;
    k_pa<<<nblocks, 256, 0, stream>>>(edge_attr, srcI, dstI, wke, cursor, srcperm, paperm,
                                      E, nblocks * 4);

    k_agg<<<(N + 15) / 16, 256, 0, stream>>>(srcperm, paperm, offs, count, a_src, a_dst,
                                             hbuf, bias, (float*)d_out, N);
}

// Round 3
// 291.236 us; speedup vs baseline: 4.9089x; 1.0650x over previous
//
#include <hip/hip_runtime.h>

#define NEG 0.2f

// h = relu(x) @ W ; a_src/a_dst via shuffle reduce. 64 nodes per 256-thread block.
__global__ __launch_bounds__(256) void k_node(
    const float* __restrict__ x, const float* __restrict__ W,
    const float* __restrict__ att_src, const float* __restrict__ att_dst,
    float* __restrict__ hbuf, float* __restrict__ a_src, float* __restrict__ a_dst, int N) {
    __shared__ float Wl[128 * 64];
    __shared__ float xs[4 * 128];
    int t = threadIdx.x;
    for (int i = t; i < 128 * 64; i += 256) Wl[i] = W[i];
    int col = t & 63;
    int nl  = t >> 6;             // 0..3 node-within-quad
    float asw = att_src[col];
    float adw = att_dst[col];
    int node0 = blockIdx.x * 64;
    __syncthreads();
    for (int it = 0; it < 16; ++it) {
        int nb = node0 + it * 4;
        __syncthreads();
        for (int j = t; j < 512; j += 256) {
            int nn = nb + (j >> 7);
            int k  = j & 127;
            xs[j] = (nn < N) ? fmaxf(x[(size_t)nn * 128 + k], 0.f) : 0.f;
        }
        __syncthreads();
        int n = nb + nl;
        float acc = 0.f;
#pragma unroll 8
        for (int k = 0; k < 128; ++k)
            acc = fmaf(xs[nl * 128 + k], Wl[k * 64 + col], acc);
        float vs = acc * asw, vd = acc * adw;
#pragma unroll
        for (int m = 1; m <= 16; m <<= 1) {
            vs += __shfl_xor(vs, m, 64);
            vd += __shfl_xor(vd, m, 64);
        }
        if (n < N) {
            hbuf[(size_t)n * 64 + col] = acc;
            if ((col & 31) == 0) {
                int hh = col >> 5;
                a_src[n * 2 + hh] = vs;
                a_dst[n * 2 + hh] = vd;
            }
        }
    }
}

// In-degree histogram (1 int atomic/edge) + wke fold (block 0).
// wke[h*64+k] = sum_c W_edge[k][h*32+c] * att_edge[h][c]
__global__ __launch_bounds__(256) void k_hist(
    const int* __restrict__ dstI, int* __restrict__ count, long long E,
    const float* __restrict__ W_edge, const float* __restrict__ att_edge,
    float* __restrict__ wke) {
    if (blockIdx.x == 0 && threadIdx.x < 128) {
        int hh = threadIdx.x >> 6;
        int k  = threadIdx.x & 63;
        float s = 0.f;
#pragma unroll
        for (int c = 0; c < 32; ++c)
            s += W_edge[k * 64 + hh * 32 + c] * att_edge[hh * 32 + c];
        wke[hh * 64 + k] = s;
    }
    long long i0 = (long long)blockIdx.x * 256 + threadIdx.x;
    long long stride = (long long)gridDim.x * 256;
    for (long long i = i0; i < E; i += stride)
        atomicAdd(&count[dstI[i]], 1);
}

// Exclusive scan, 1024 elements per block (256 thr x 4).
__global__ __launch_bounds__(256) void k_scan1(const int* __restrict__ cnt, int* __restrict__ offs,
                                               int* __restrict__ bsum, int N) {
    __shared__ int ts[256];
    int t = threadIdx.x, blk = blockIdx.x;
    int base = blk * 1024 + t * 4;
    int v[4], s = 0;
#pragma unroll
    for (int i = 0; i < 4; ++i) {
        int idx = base + i;
        v[i] = (idx < N) ? cnt[idx] : 0;
        s += v[i];
    }
    ts[t] = s;
    __syncthreads();
    for (int off = 1; off < 256; off <<= 1) {
        int y = (t >= off) ? ts[t - off] : 0;
        __syncthreads();
        ts[t] += y;
        __syncthreads();
    }
    int run = ts[t] - s;   // exclusive prefix of this thread's chunk
#pragma unroll
    for (int i = 0; i < 4; ++i) {
        int idx = base + i;
        if (idx < N) offs[idx] = run;
        run += v[i];
    }
    if (t == 255) bsum[blk] = ts[255];
}

// Single-wave shuffle scan over block sums (nb <= 64).
__global__ void k_scan2(int* __restrict__ bsum, int nb) {
    int t = threadIdx.x;   // 64 threads
    int orig = (t < nb) ? bsum[t] : 0;
    int v = orig;
#pragma unroll
    for (int off = 1; off < 64; off <<= 1) {
        int y = __shfl_up(v, off, 64);
        if (t >= off) v += y;
    }
    if (t < nb) bsum[t] = v - orig;   // exclusive
}

__global__ void k_scan3(int* __restrict__ offs, const int* __restrict__ bsum,
                        int* __restrict__ cursor, int N) {
    int idx = blockIdx.x * 256 + threadIdx.x;
    if (idx < N) {
        int o = offs[idx] + bsum[idx >> 10];
        offs[idx] = o;
        cursor[idx] = o;
    }
}

// Edge sweep: a_edge dot (16-lane reduce over edge_attr row) + CSR scatter.
// Packs (pa0, pa1, src) into one float4 per edge.
__global__ __launch_bounds__(256) void k_pa(
    const float* __restrict__ edge_attr, const int* __restrict__ srcI,
    const int* __restrict__ dstI, const float* __restrict__ wke,
    int* __restrict__ cursor, float4* __restrict__ evec,
    long long E, int nwaves_total) {
    int lane = threadIdx.x & 63;
    int sub  = lane & 15;
    int grp  = lane >> 4;
    long long wave = (long long)blockIdx.x * 4 + (threadIdx.x >> 6);
    float w0[4], w1[4];
#pragma unroll
    for (int j = 0; j < 4; ++j) {
        w0[j] = wke[sub * 4 + j];
        w1[j] = wke[64 + sub * 4 + j];
    }
    for (long long base = wave * 4; base < E; base += (long long)nwaves_total * 4) {
        long long e = base + grp;
        bool valid = e < E;
        float pa0 = 0.f, pa1 = 0.f;
        if (valid) {
            const float4 ea = *(const float4*)(edge_attr + e * 64 + sub * 4);
            pa0 = ea.x * w0[0] + ea.y * w0[1] + ea.z * w0[2] + ea.w * w0[3];
            pa1 = ea.x * w1[0] + ea.y * w1[1] + ea.z * w1[2] + ea.w * w1[3];
        }
#pragma unroll
        for (int m = 1; m <= 8; m <<= 1) {
            pa0 += __shfl_xor(pa0, m, 64);
            pa1 += __shfl_xor(pa1, m, 64);
        }
        if (valid && sub == 0) {
            int s = srcI[e], d = dstI[e];
            int pos = atomicAdd(&cursor[d], 1);
            evec[pos] = make_float4(pa0, pa1, __int_as_float(s), 0.f);
        }
    }
}

// Per-node aggregation: 64 lanes/node, 4-way edge-parallel, software-pipelined.
// sub = col group (16 cols of 4 floats), grp = edge stride lane.
__global__ __launch_bounds__(256) void k_agg(
    const float4* __restrict__ evec, const int* __restrict__ offs,
    const int* __restrict__ count, const float* __restrict__ a_src,
    const float* __restrict__ a_dst, const float* __restrict__ hbuf,
    const float* __restrict__ bias, float* __restrict__ out, int N) {
    int t = threadIdx.x;
    int lane = t & 63;
    int sub = lane & 15;
    int grp = lane >> 4;
    int n = blockIdx.x * 4 + (t >> 6);
    if (n >= N) return;
    int cnt  = count[n];
    int base = offs[n];
    float ad0 = a_dst[n * 2 + 0], ad1 = a_dst[n * 2 + 1];
    float accx = 0.f, accy = 0.f, accz = 0.f, accw = 0.f;
    float den0 = 0.f, den1 = 0.f, sae0 = 0.f, sae1 = 0.f;

    if (cnt > 0) {
        int last = cnt - 1;
        float4 evA = evec[base + (grp < cnt ? grp : last)];
        float4 evB = evec[base + (grp + 4 < cnt ? grp + 4 : last)];
        int sA = __float_as_int(evA.z);
        int sB = __float_as_int(evB.z);
        float2 asA = *(const float2*)(a_src + 2 * (size_t)sA);
        float4 hvA = *(const float4*)(hbuf + (size_t)sA * 64 + sub * 4);
        for (int j = grp; j < cnt; j += 4) {
            int jc = j + 8 < cnt ? j + 8 : last;
            float4 evC = evec[base + jc];
            float2 asB = *(const float2*)(a_src + 2 * (size_t)sB);
            float4 hvB = *(const float4*)(hbuf + (size_t)sB * 64 + sub * 4);
            // compute with stage-A state
            float l0 = asA.x + ad0 + evA.x; l0 = l0 > 0.f ? l0 : NEG * l0;
            float l1 = asA.y + ad1 + evA.y; l1 = l1 > 0.f ? l1 : NEG * l1;
            float q0 = __expf(l0), q1 = __expf(l1);
            float q = (sub < 8) ? q0 : q1;
            accx = fmaf(q, hvA.x, accx);
            accy = fmaf(q, hvA.y, accy);
            accz = fmaf(q, hvA.z, accz);
            accw = fmaf(q, hvA.w, accw);
            den0 += q0; den1 += q1;
            sae0 += evA.x; sae1 += evA.y;
            // shift pipeline
            evA = evB; sA = sB; asA = asB; hvA = hvB;
            evB = evC; sB = __float_as_int(evC.z);
        }
    }
    // reduce across the 4 edge groups (lane bits 4,5)
#define RED2(v) { v += __shfl_xor(v, 16, 64); v += __shfl_xor(v, 32, 64); }
    RED2(accx) RED2(accy) RED2(accz) RED2(accw)
    RED2(den0) RED2(den1) RED2(sae0) RED2(sae1)
#undef RED2

    float dg = (cnt > 0) ? (float)cnt : 1.f;
    float as0 = a_src[n * 2 + 0], as1 = a_src[n * 2 + 1];
    float l0 = as0 + ad0 + sae0 / dg; l0 = l0 > 0.f ? l0 : NEG * l0;
    float l1 = as1 + ad1 + sae1 / dg; l1 = l1 > 0.f ? l1 : NEG * l1;
    float pl0 = __expf(l0), pl1 = __expf(l1);
    const float4 hn = *(const float4*)(hbuf + (size_t)n * 64 + sub * 4);
    float pl  = (sub < 8) ? pl0 : pl1;
    float den = ((sub < 8) ? den0 + pl0 : den1 + pl1) + 1e-16f;
    const float4 bv = *(const float4*)(bias + sub * 4);
    if (grp == 0) {
        float4 o;
        o.x = (accx + pl * hn.x) / den + bv.x;
        o.y = (accy + pl * hn.y) / den + bv.y;
        o.z = (accz + pl * hn.z) / den + bv.z;
        o.w = (accw + pl * hn.w) / den + bv.w;
        *(float4*)(out + (size_t)n * 64 + sub * 4) = o;
    }
}

extern "C" void kernel_launch(void* const* d_in, const int* in_sizes, int n_in,
                              void* d_out, int out_size, void* d_ws, size_t ws_size,
                              hipStream_t stream) {
    const float* x         = (const float*)d_in[0];
    const int*   ei        = (const int*)d_in[1];
    const float* edge_attr = (const float*)d_in[2];
    const float* W         = (const float*)d_in[3];
    const float* W_edge    = (const float*)d_in[4];
    const float* att_src   = (const float*)d_in[5];
    const float* att_dst   = (const float*)d_in[6];
    const float* att_edge  = (const float*)d_in[7];
    const float* bias      = (const float*)d_in[8];

    int N = in_sizes[0] / 128;
    long long E = in_sizes[1] / 2;
    const int* srcI = ei;
    const int* dstI = ei + E;

    // Workspace layout (16B-aligned first)
    char* ws = (char*)d_ws;
    float4* evec  = (float4*)ws;                      ws += (size_t)E * 16;
    float* wke    = (float*)ws;                       ws += 128 * 4;
    float* hbuf   = (float*)ws;                       ws += (size_t)N * 64 * 4;
    float* a_src  = (float*)ws;                       ws += (size_t)N * 2 * 4;
    float* a_dst  = (float*)ws;                       ws += (size_t)N * 2 * 4;
    int*   count  = (int*)ws;                         ws += (size_t)N * 4;
    int*   offs   = (int*)ws;                         ws += (size_t)N * 4;
    int*   cursor = (int*)ws;                         ws += (size_t)N * 4;
    int*   bsum   = (int*)ws;                         ws += 64 * 4;

    hipMemsetAsync(count, 0, (size_t)N * sizeof(int), stream);

    k_node<<<(N + 63) / 64, 256, 0, stream>>>(x, W, att_src, att_dst, hbuf, a_src, a_dst, N);
    k_hist<<<2048, 256, 0, stream>>>(dstI, count, E, W_edge, att_edge, wke);

    int nb = (N + 1023) / 1024;
    k_scan1<<<nb, 256, 0, stream>>>(count, offs, bsum, N);
    k_scan2<<<1, 64, 0, stream>>>(bsum, nb);
    k_scan3<<<(N + 255) / 256, 256, 0, stream>>>(offs, bsum, cursor, N);

    int nblocks = 2048;
    k_pa<<<nblocks, 256, 0, stream>>>(edge_attr, srcI, dstI, wke, cursor, evec, E, nblocks * 4);

    k_agg<<<(N + 3) / 4, 256, 0, stream>>>(evec, offs, count, a_src, a_dst, hbuf, bias,
                                           (float*)d_out, N);
}